// Round 8
// baseline (251.635 us; speedup 1.0000x reference)
//
#include <hip/hip_runtime.h>
#include <hip/hip_bf16.h>

using bf16 = __hip_bfloat16;
typedef __attribute__((ext_vector_type(4))) float f32x4;
typedef __attribute__((ext_vector_type(8))) short short8;

#define SEQ 4096
#define DIM 768
#define LDQ 800    // padded leading dim for xc/W/Q/Kb (breaks L1 set aliasing)
#define LDP 4128   // padded leading dim for P/Vt (8256B stride: set+1 per row)

// Proven: fp32 in / fp32 out, bf16 internals. r8: zero-LDS direct-load GEMM
// cores (no barriers -> compiler emits fine-grained per-load vmcnt instead of
// the vmcnt(0) barrier drain that plateaus the LDS structure), padded strides.

// ---- fused fp32 -> bf16 canonicalization (row-aware, writes padded ld) ----
__global__ void convert_all_kernel(const float* __restrict__ x,
                                   const float* __restrict__ wq,
                                   const float* __restrict__ wk,
                                   const float* __restrict__ wv,
                                   bf16* __restrict__ xc, bf16* __restrict__ wqc,
                                   bf16* __restrict__ wkc, bf16* __restrict__ wvc,
                                   float* __restrict__ denom) {
  const int XB = SEQ * 96 / 256;   // 1536 blocks for x  (96 threads span a row)
  const int WB = DIM * 96 / 256;   // 288 per W
  int b = blockIdx.x;
  if (b == 0) {  // zero denom[4096]
    float4 z = {0.f, 0.f, 0.f, 0.f};
#pragma unroll
    for (int q = 0; q < 4; q++)
      *(float4*)(denom + threadIdx.x * 4 + q * 1024) = z;
  }
  const float* src; bf16* dst; int t;
  if (b < XB)               { src = x;  dst = xc;  t = b * 256 + threadIdx.x; }
  else if (b < XB + WB)     { src = wq; dst = wqc; t = (b - XB) * 256 + threadIdx.x; }
  else if (b < XB + 2 * WB) { src = wk; dst = wkc; t = (b - XB - WB) * 256 + threadIdx.x; }
  else                      { src = wv; dst = wvc; t = (b - XB - 2 * WB) * 256 + threadIdx.x; }
  int row = t / 96;
  int col = (t - row * 96) * 8;
  const float* s = src + row * DIM + col;
  float4 f0 = *(const float4*)s;
  float4 f1 = *(const float4*)(s + 4);
  bf16 tmp[8];
  tmp[0] = __float2bfloat16(f0.x); tmp[1] = __float2bfloat16(f0.y);
  tmp[2] = __float2bfloat16(f0.z); tmp[3] = __float2bfloat16(f0.w);
  tmp[4] = __float2bfloat16(f1.x); tmp[5] = __float2bfloat16(f1.y);
  tmp[6] = __float2bfloat16(f1.z); tmp[7] = __float2bfloat16(f1.w);
  *(uint4*)(dst + row * LDQ + col) = *(const uint4*)tmp;
}

// ============ direct-load BT-GEMM core: no LDS, no barriers ============
// A,B row-major bf16 with leading dim ldk. C[m,n] = sum_k A[m,k]B[n,k].
// Each wave: 64x64 tile, 4x4 frags of 16x16x32. Frags loaded straight from
// global (L1/L2-served); compiler schedules loads w/ per-dep vmcnt, TLP at
// 4 waves/SIMD hides L2 latency. Tiles are L2-resident (padded strides avoid
// L1 set aliasing).
__device__ __forceinline__ void gemm_direct(const bf16* __restrict__ A,
                                            const bf16* __restrict__ B,
                                            int ldk, int klen, int m0, int n0,
                                            f32x4 acc[4][4]) {
  const int tid = threadIdx.x;
  const int wave = tid >> 6, lane = tid & 63;
  const int wm = (wave & 1) * 64, wn = (wave >> 1) * 64;
  const int g = lane >> 4, lr = lane & 15;
  const bf16* Ab = A + (size_t)(m0 + wm + lr) * ldk + g * 8;
  const bf16* Bb = B + (size_t)(n0 + wn + lr) * ldk + g * 8;
  const size_t r16 = (size_t)16 * ldk;
  for (int kk = 0; kk < klen; kk += 32) {
    short8 af[4], bfr[4];
#pragma unroll
    for (int i = 0; i < 4; i++)
      af[i] = *(const short8*)(Ab + i * r16 + kk);
#pragma unroll
    for (int j = 0; j < 4; j++)
      bfr[j] = *(const short8*)(Bb + j * r16 + kk);
#pragma unroll
    for (int i = 0; i < 4; i++)
#pragma unroll
      for (int j = 0; j < 4; j++)
        acc[i][j] = __builtin_amdgcn_mfma_f32_16x16x32_bf16(af[i], bfr[j], acc[i][j], 0, 0, 0);
  }
}

// C/D layout (verified m89/m91): col = lane&15, row = (lane>>4)*4 + reg.

// ---- K1: fused QKV projection. grid (32, 18). Q gets softmax scale folded;
// V transposed via LDS tile (LDS free now that gemm is direct).
__global__ __launch_bounds__(256, 4) void qkv_kernel(
    const bf16* __restrict__ x, const bf16* __restrict__ Wq,
    const bf16* __restrict__ Wk, const bf16* __restrict__ Wv,
    bf16* __restrict__ Q, bf16* __restrict__ Kb, bf16* __restrict__ Vt) {
  __shared__ __align__(16) bf16 tile[128 * 67];
  const int m0  = blockIdx.x * 128;
  const int n0g = blockIdx.y * 128;
  const int wsel = n0g / DIM;          // 0=Q 1=K 2=V (uniform per block)
  const int n0   = n0g % DIM;
  const bf16* W = (wsel == 0) ? Wq : (wsel == 1) ? Wk : Wv;
  f32x4 acc[4][4] = {};
  gemm_direct(x, W, LDQ, DIM, m0, n0, acc);

  const int tid = threadIdx.x, wave = tid >> 6, lane = tid & 63;
  const int wm = (wave & 1) * 64, wn = (wave >> 1) * 64;
  const int g = lane >> 4, lr = lane & 15;
  const float scale = 0.03608439182435161f;  // 1/sqrt(768)

  if (wsel == 2) {
    // Two-phase 128x64 LDS transpose; stride 67 spreads banks.
#pragma unroll
    for (int ph = 0; ph < 2; ph++) {
      __syncthreads();
      if ((wave >> 1) == ph) {
#pragma unroll
        for (int i = 0; i < 4; i++)
#pragma unroll
          for (int j = 0; j < 4; j++)
#pragma unroll
            for (int r = 0; r < 4; r++)
              tile[(wm + i * 16 + g * 4 + r) * 67 + j * 16 + lr] =
                  __float2bfloat16(acc[i][j][r]);
      }
      __syncthreads();
      int cl = tid >> 2;          // column within this 64-col half
      int r0 = (tid & 3) * 32;    // row segment
      bf16 vals[32];
#pragma unroll
      for (int k = 0; k < 32; k++) vals[k] = tile[(r0 + k) * 67 + cl];
      bf16* dst = Vt + (size_t)(n0 + ph * 64 + cl) * LDP + m0 + r0;
#pragma unroll
      for (int q = 0; q < 4; q++)
        *(uint4*)(dst + q * 8) = *(const uint4*)(vals + q * 8);
    }
  } else {
    bf16* dstm = (wsel == 0) ? Q : Kb;
    float fs = (wsel == 0) ? scale : 1.0f;
#pragma unroll
    for (int i = 0; i < 4; i++)
#pragma unroll
      for (int j = 0; j < 4; j++)
#pragma unroll
        for (int r = 0; r < 4; r++) {
          int row = m0 + wm + i * 16 + g * 4 + r;
          int col = n0 + wn + j * 16 + lr;
          dstm[row * LDQ + col] = __float2bfloat16(acc[i][j][r] * fs);
        }
  }
}

// ---- K2: S = Q K^T; P = exp(S) (|logit| <~ 2); row sums -> denom. grid (32,32).
__global__ __launch_bounds__(256, 4) void score_kernel(
    const bf16* __restrict__ Q, const bf16* __restrict__ Kb,
    bf16* __restrict__ P, float* __restrict__ denom) {
  const int m0 = blockIdx.x * 128;
  const int n0 = blockIdx.y * 128;
  f32x4 acc[4][4] = {};
  gemm_direct(Q, Kb, LDQ, DIM, m0, n0, acc);

  const int tid = threadIdx.x, wave = tid >> 6, lane = tid & 63;
  const int wm = (wave & 1) * 64, wn = (wave >> 1) * 64;
  const int g = lane >> 4, lr = lane & 15;
#pragma unroll
  for (int i = 0; i < 4; i++) {
    float rsum[4] = {0.f, 0.f, 0.f, 0.f};
#pragma unroll
    for (int j = 0; j < 4; j++)
#pragma unroll
      for (int r = 0; r < 4; r++) {
        float p = __expf(acc[i][j][r]);
        int row = m0 + wm + i * 16 + g * 4 + r;
        int col = n0 + wn + j * 16 + lr;
        P[(size_t)row * LDP + col] = __float2bfloat16(p);
        rsum[r] += p;
      }
#pragma unroll
    for (int r = 0; r < 4; r++) {
      float s = rsum[r];
      s += __shfl_xor(s, 1);
      s += __shfl_xor(s, 2);
      s += __shfl_xor(s, 4);
      s += __shfl_xor(s, 8);
      if (lr == 0) atomicAdd(&denom[m0 + wm + i * 16 + g * 4 + r], s);
    }
  }
}

// ---- K3a: split-K PV. grid (32, 6, 4); z picks K-chunk of 1024. bf16 partials.
__global__ __launch_bounds__(256, 4) void pv_kernel(
    const bf16* __restrict__ P, const bf16* __restrict__ Vt,
    bf16* __restrict__ partial) {
  const int m0 = blockIdx.x * 128;
  const int n0 = blockIdx.y * 128;
  const int kbase = blockIdx.z * (SEQ / 4);
  f32x4 acc[4][4] = {};
  gemm_direct(P + kbase, Vt + kbase, LDP, SEQ / 4, m0, n0, acc);

  bf16* pout = partial + (size_t)blockIdx.z * SEQ * DIM;
  const int tid = threadIdx.x, wave = tid >> 6, lane = tid & 63;
  const int wm = (wave & 1) * 64, wn = (wave >> 1) * 64;
  const int g = lane >> 4, lr = lane & 15;
#pragma unroll
  for (int i = 0; i < 4; i++)
#pragma unroll
    for (int j = 0; j < 4; j++)
#pragma unroll
      for (int r = 0; r < 4; r++) {
        int row = m0 + wm + i * 16 + g * 4 + r;
        int col = n0 + wn + j * 16 + lr;
        pout[row * DIM + col] = __float2bfloat16(acc[i][j][r]);
      }
}

// ---- K3b: out = (sum_z partial[z]) / denom[row]. 8 elems/thread.
__global__ __launch_bounds__(256) void reduce_kernel(
    const bf16* __restrict__ partial, const float* __restrict__ denom,
    float* __restrict__ out) {
  const size_t stride = (size_t)SEQ * DIM;
  int i = (blockIdx.x * 256 + threadIdx.x) * 8;
  uint4 u0 = *(const uint4*)(partial + i);
  uint4 u1 = *(const uint4*)(partial + stride + i);
  uint4 u2 = *(const uint4*)(partial + 2 * stride + i);
  uint4 u3 = *(const uint4*)(partial + 3 * stride + i);
  bf16 a0[8], a1[8], a2[8], a3[8];
  *(uint4*)a0 = u0; *(uint4*)a1 = u1; *(uint4*)a2 = u2; *(uint4*)a3 = u3;
  float inv = 1.0f / denom[i / DIM];
  float o[8];
#pragma unroll
  for (int k = 0; k < 8; k++)
    o[k] = (__bfloat162float(a0[k]) + __bfloat162float(a1[k]) +
            __bfloat162float(a2[k]) + __bfloat162float(a3[k])) * inv;
  *(float4*)(out + i)     = *(const float4*)(o);
  *(float4*)(out + i + 4) = *(const float4*)(o + 4);
}

extern "C" void kernel_launch(void* const* d_in, const int* in_sizes, int n_in,
                              void* d_out, int out_size, void* d_ws, size_t ws_size,
                              hipStream_t stream) {
  const float* x_raw  = (const float*)d_in[0];
  const float* Wq_raw = (const float*)d_in[1];
  const float* Wk_raw = (const float*)d_in[2];
  const float* Wv_raw = (const float*)d_in[3];
  float* out = (float*)d_out;

  // ws layout (~89 MB), padded leading dims:
  //   xc [4096][800], Wqc/Wkc/Wvc [768][800]   bf16
  //   Q [4096][800] (pre-scaled), Kb [4096][800], Vt [768][4128]  bf16
  //   P [4096][4128] bf16, denom f32 [4096], partial bf16 [4][4096][768]
  bf16* xc  = (bf16*)d_ws;
  bf16* Wqc = xc  + (size_t)SEQ * LDQ;
  bf16* Wkc = Wqc + (size_t)DIM * LDQ;
  bf16* Wvc = Wkc + (size_t)DIM * LDQ;
  bf16* Q   = Wvc + (size_t)DIM * LDQ;
  bf16* Kb  = Q   + (size_t)SEQ * LDQ;
  bf16* Vt  = Kb  + (size_t)SEQ * LDQ;
  bf16* P   = Vt  + (size_t)DIM * LDP;
  float* denom  = (float*)(P + (size_t)SEQ * LDP);
  bf16* partial = (bf16*)(denom + SEQ);

  const int conv_blocks = SEQ * 96 / 256 + 3 * (DIM * 96 / 256);  // 1536+864

  convert_all_kernel<<<conv_blocks, 256, 0, stream>>>(
      x_raw, Wq_raw, Wk_raw, Wv_raw, xc, Wqc, Wkc, Wvc, denom);
  qkv_kernel<<<dim3(SEQ / 128, 2304 / 128), 256, 0, stream>>>(xc, Wqc, Wkc, Wvc, Q, Kb, Vt);
  score_kernel<<<dim3(SEQ / 128, SEQ / 128), 256, 0, stream>>>(Q, Kb, P, denom);
  pv_kernel<<<dim3(SEQ / 128, DIM / 128, 4), 256, 0, stream>>>(P, Vt, partial);
  reduce_kernel<<<SEQ * DIM / 8 / 256, 256, 0, stream>>>(partial, denom, out);
}

// Round 9
// 192.286 us; speedup vs baseline: 1.3086x; 1.3086x over previous
//
#include <hip/hip_runtime.h>
#include <hip/hip_bf16.h>

using bf16 = __hip_bfloat16;
typedef __attribute__((ext_vector_type(4))) float f32x4;
typedef __attribute__((ext_vector_type(8))) short short8;

#define SEQ 4096
#define DIM 768

// Proven: fp32 in / fp32 out, bf16 internals. r9 = r7 core (BK=64 LDS-DMA,
// the measured local optimum; r8's direct-load core was latency-bound and
// regressed) + pv folds 1/denom and atomically accumulates into out (reduce
// kernel and partial buffer eliminated; out zeroed in convert).

// ---- fused fp32 -> bf16 canonicalization + denom/out zeroing ----
__global__ void convert_all_kernel(const float* __restrict__ x,
                                   const float* __restrict__ wq,
                                   const float* __restrict__ wk,
                                   const float* __restrict__ wv,
                                   bf16* __restrict__ xc, bf16* __restrict__ wqc,
                                   bf16* __restrict__ wkc, bf16* __restrict__ wvc,
                                   float* __restrict__ denom,
                                   float* __restrict__ out) {
  const int XB = (SEQ * DIM) / 2048;   // 1536
  const int WB = (DIM * DIM) / 2048;   // 288
  int b = blockIdx.x;
  if (b == 0) {  // zero denom[4096]
    float4 z = {0.f, 0.f, 0.f, 0.f};
#pragma unroll
    for (int q = 0; q < 4; q++)
      *(float4*)(denom + threadIdx.x * 4 + q * 1024) = z;
  }
  const float* src; bf16* dst; int off;
  if (b < XB) {
    src = x; dst = xc; off = b * 2048;
    // zero out[] (same element count as x: 4096*768); harness poisons it.
    float4 z = {0.f, 0.f, 0.f, 0.f};
    float* o = out + off + threadIdx.x * 8;
    *(float4*)o = z; *(float4*)(o + 4) = z;
  }
  else if (b < XB + WB)     { src = wq; dst = wqc; off = (b - XB) * 2048; }
  else if (b < XB + 2 * WB) { src = wk; dst = wkc; off = (b - XB - WB) * 2048; }
  else                      { src = wv; dst = wvc; off = (b - XB - 2 * WB) * 2048; }
  int i = off + threadIdx.x * 8;
  float4 f0 = *(const float4*)(src + i);
  float4 f1 = *(const float4*)(src + i + 4);
  bf16 tmp[8];
  tmp[0] = __float2bfloat16(f0.x); tmp[1] = __float2bfloat16(f0.y);
  tmp[2] = __float2bfloat16(f0.z); tmp[3] = __float2bfloat16(f0.w);
  tmp[4] = __float2bfloat16(f1.x); tmp[5] = __float2bfloat16(f1.y);
  tmp[6] = __float2bfloat16(f1.z); tmp[7] = __float2bfloat16(f1.w);
  *(uint4*)(dst + i) = *(const uint4*)tmp;
}

// ============ BT-GEMM core (BK=64, two BK=32 planes, LDS-DMA) ============
__device__ __forceinline__ void gload_lds16(const bf16* g, bf16* l) {
  __builtin_amdgcn_global_load_lds(
      (const __attribute__((address_space(1))) void*)g,
      (__attribute__((address_space(3))) void*)l,
      16, 0, 0);
}

__device__ __forceinline__ void stage64(const bf16* g, int ldk, bf16* l,
                                        int wave, int lane) {
  int r = lane >> 2;            // 0..15
  int c = (lane & 3) * 8;       // 0,8,16,24
  const bf16* gw = g + (size_t)(wave * 32) * ldk;
  bf16* lw = l + wave * 1024;
#pragma unroll
  for (int h = 0; h < 2; h++)
#pragma unroll
    for (int s = 0; s < 2; s++)
      gload_lds16(gw + (size_t)(s * 16 + r) * ldk + h * 32 + c,
                  lw + h * 4096 + s * 512);
}

__device__ __forceinline__ void gemm_core(const bf16* __restrict__ A,
                                          const bf16* __restrict__ B,
                                          int ldk, int klen, int m0, int n0,
                                          f32x4 acc[4][4],
                                          bf16* lA, bf16* lB) {
  const int tid  = threadIdx.x;
  const int wave = tid >> 6, lane = tid & 63;
  const int wm = (wave & 1) * 64, wn = (wave >> 1) * 64;
  const int g = lane >> 4, lr = lane & 15;
  const bf16* Abase = A + (size_t)m0 * ldk;
  const bf16* Bbase = B + (size_t)n0 * ldk;
  for (int kk = 0; kk < klen; kk += 64) {
    stage64(Abase + kk, ldk, lA, wave, lane);
    stage64(Bbase + kk, ldk, lB, wave, lane);
    __syncthreads();  // vmcnt drain (DMA done) + barrier
#pragma unroll
    for (int h = 0; h < 2; h++) {
      short8 af[4], bfr[4];
#pragma unroll
      for (int i = 0; i < 4; i++)
        af[i] = *(const short8*)&lA[h * 4096 + (wm + i * 16 + lr) * 32 + g * 8];
#pragma unroll
      for (int j = 0; j < 4; j++)
        bfr[j] = *(const short8*)&lB[h * 4096 + (wn + j * 16 + lr) * 32 + g * 8];
#pragma unroll
      for (int i = 0; i < 4; i++)
#pragma unroll
        for (int j = 0; j < 4; j++)
          acc[i][j] = __builtin_amdgcn_mfma_f32_16x16x32_bf16(af[i], bfr[j], acc[i][j], 0, 0, 0);
    }
    __syncthreads();
  }
}

// C/D layout (verified m89/m91): col = lane&15, row = (lane>>4)*4 + reg.

// ---- K1: fused QKV projection. grid (32, 18). Q gets softmax scale folded;
// V written transposed via LDS transpose (coalesced Vt stores).
__global__ __launch_bounds__(256, 3) void qkv_kernel(
    const bf16* __restrict__ x, const bf16* __restrict__ Wq,
    const bf16* __restrict__ Wk, const bf16* __restrict__ Wv,
    bf16* __restrict__ Q, bf16* __restrict__ Kb, bf16* __restrict__ Vt) {
  __shared__ __align__(16) bf16 smem[16384];  // lA|lB for gemm; tile for transpose
  bf16* lA = smem;
  bf16* lB = smem + 8192;
  const int m0  = blockIdx.x * 128;
  const int n0g = blockIdx.y * 128;
  const int wsel = n0g / DIM;          // 0=Q 1=K 2=V (uniform per block)
  const int n0   = n0g % DIM;
  const bf16* W = (wsel == 0) ? Wq : (wsel == 1) ? Wk : Wv;
  f32x4 acc[4][4] = {};
  gemm_core(x, W, DIM, DIM, m0, n0, acc, lA, lB);

  const int tid = threadIdx.x, wave = tid >> 6, lane = tid & 63;
  const int wm = (wave & 1) * 64, wn = (wave >> 1) * 64;
  const int g = lane >> 4, lr = lane & 15;
  const float scale = 0.03608439182435161f;  // 1/sqrt(768)

  if (wsel == 2) {
    // Two-phase 128x64 LDS transpose; stride 67 spreads banks.
    bf16* tile = smem;
#pragma unroll
    for (int ph = 0; ph < 2; ph++) {
      __syncthreads();
      if ((wave >> 1) == ph) {
#pragma unroll
        for (int i = 0; i < 4; i++)
#pragma unroll
          for (int j = 0; j < 4; j++)
#pragma unroll
            for (int r = 0; r < 4; r++)
              tile[(wm + i * 16 + g * 4 + r) * 67 + j * 16 + lr] =
                  __float2bfloat16(acc[i][j][r]);
      }
      __syncthreads();
      int cl = tid >> 2;          // column within this 64-col half
      int r0 = (tid & 3) * 32;    // row segment
      bf16 vals[32];
#pragma unroll
      for (int k = 0; k < 32; k++) vals[k] = tile[(r0 + k) * 67 + cl];
      bf16* dst = Vt + (size_t)(n0 + ph * 64 + cl) * SEQ + m0 + r0;
#pragma unroll
      for (int q = 0; q < 4; q++)
        *(uint4*)(dst + q * 8) = *(const uint4*)(vals + q * 8);
    }
  } else {
    bf16* dstm = (wsel == 0) ? Q : Kb;
    float fs = (wsel == 0) ? scale : 1.0f;
#pragma unroll
    for (int i = 0; i < 4; i++)
#pragma unroll
      for (int j = 0; j < 4; j++)
#pragma unroll
        for (int r = 0; r < 4; r++) {
          int row = m0 + wm + i * 16 + g * 4 + r;
          int col = n0 + wn + j * 16 + lr;
          dstm[row * DIM + col] = __float2bfloat16(acc[i][j][r] * fs);
        }
  }
}

// ---- K2: S = Q K^T; P = exp(S) (|logit| <~ 2, no max-sub); row sums -> denom.
__global__ __launch_bounds__(256, 3) void score_kernel(
    const bf16* __restrict__ Q, const bf16* __restrict__ Kb,
    bf16* __restrict__ P, float* __restrict__ denom) {
  __shared__ __align__(16) bf16 smem[16384];
  bf16* lA = smem;
  bf16* lB = smem + 8192;
  const int m0 = blockIdx.x * 128;
  const int n0 = blockIdx.y * 128;
  f32x4 acc[4][4] = {};
  gemm_core(Q, Kb, DIM, DIM, m0, n0, acc, lA, lB);

  const int tid = threadIdx.x, wave = tid >> 6, lane = tid & 63;
  const int wm = (wave & 1) * 64, wn = (wave >> 1) * 64;
  const int g = lane >> 4, lr = lane & 15;
#pragma unroll
  for (int i = 0; i < 4; i++) {
    float rsum[4] = {0.f, 0.f, 0.f, 0.f};
#pragma unroll
    for (int j = 0; j < 4; j++)
#pragma unroll
      for (int r = 0; r < 4; r++) {
        float p = __expf(acc[i][j][r]);
        int row = m0 + wm + i * 16 + g * 4 + r;
        int col = n0 + wn + j * 16 + lr;
        P[(size_t)row * SEQ + col] = __float2bfloat16(p);
        rsum[r] += p;
      }
#pragma unroll
    for (int r = 0; r < 4; r++) {
      float s = rsum[r];
      s += __shfl_xor(s, 1);
      s += __shfl_xor(s, 2);
      s += __shfl_xor(s, 4);
      s += __shfl_xor(s, 8);
      if (lr == 0) atomicAdd(&denom[m0 + wm + i * 16 + g * 4 + r], s);
    }
  }
}

// ---- K3: split-K PV, scaled accumulate into out. grid (32, 6, 4).
// out was zeroed by convert; denom is final after score. Each z-chunk adds
// (P_chunk @ Vt_chunk^T) / denom[row] via fp32 atomics (distinct addresses,
// 4-way/elem across z).
__global__ __launch_bounds__(256, 3) void pv_kernel(
    const bf16* __restrict__ P, const bf16* __restrict__ Vt,
    const float* __restrict__ denom, float* __restrict__ out) {
  __shared__ __align__(16) bf16 smem[16384];
  bf16* lA = smem;
  bf16* lB = smem + 8192;
  const int m0 = blockIdx.x * 128;
  const int n0 = blockIdx.y * 128;
  const int kbase = blockIdx.z * (SEQ / 4);
  f32x4 acc[4][4] = {};
  gemm_core(P + kbase, Vt + kbase, SEQ, SEQ / 4, m0, n0, acc, lA, lB);

  const int tid = threadIdx.x, wave = tid >> 6, lane = tid & 63;
  const int wm = (wave & 1) * 64, wn = (wave >> 1) * 64;
  const int g = lane >> 4, lr = lane & 15;
#pragma unroll
  for (int i = 0; i < 4; i++) {
    float inv[4];
#pragma unroll
    for (int r = 0; r < 4; r++)
      inv[r] = 1.0f / denom[m0 + wm + i * 16 + g * 4 + r];
#pragma unroll
    for (int j = 0; j < 4; j++)
#pragma unroll
      for (int r = 0; r < 4; r++) {
        int row = m0 + wm + i * 16 + g * 4 + r;
        int col = n0 + wn + j * 16 + lr;
        atomicAdd(&out[row * DIM + col], acc[i][j][r] * inv[r]);
      }
  }
}

extern "C" void kernel_launch(void* const* d_in, const int* in_sizes, int n_in,
                              void* d_out, int out_size, void* d_ws, size_t ws_size,
                              hipStream_t stream) {
  const float* x_raw  = (const float*)d_in[0];
  const float* Wq_raw = (const float*)d_in[1];
  const float* Wk_raw = (const float*)d_in[2];
  const float* Wv_raw = (const float*)d_in[3];
  float* out = (float*)d_out;

  // ws layout (~67 MB):
  //   xc bf16 [4096][768], Wqc/Wkc/Wvc bf16 [768][768]
  //   Q bf16 [4096][768] (pre-scaled), Kb bf16 [4096][768], Vt bf16 [768][4096]
  //   P bf16 [4096][4096], denom f32 [4096]
  bf16* xc  = (bf16*)d_ws;
  bf16* Wqc = xc  + (size_t)SEQ * DIM;
  bf16* Wkc = Wqc + (size_t)DIM * DIM;
  bf16* Wvc = Wkc + (size_t)DIM * DIM;
  bf16* Q   = Wvc + (size_t)DIM * DIM;
  bf16* Kb  = Q   + (size_t)SEQ * DIM;
  bf16* Vt  = Kb  + (size_t)SEQ * DIM;
  bf16* P   = Vt  + (size_t)DIM * SEQ;
  float* denom = (float*)(P + (size_t)SEQ * SEQ);

  const int nx = SEQ * DIM;   // 3,145,728
  const int nw = DIM * DIM;   //   589,824
  const int conv_blocks = nx / 2048 + 3 * (nw / 2048);  // 2400

  convert_all_kernel<<<conv_blocks, 256, 0, stream>>>(
      x_raw, Wq_raw, Wk_raw, Wv_raw, xc, Wqc, Wkc, Wvc, denom, out);
  qkv_kernel<<<dim3(SEQ / 128, 2304 / 128), 256, 0, stream>>>(xc, Wqc, Wkc, Wvc, Q, Kb, Vt);
  score_kernel<<<dim3(SEQ / 128, SEQ / 128), 256, 0, stream>>>(Q, Kb, P, denom);
  pv_kernel<<<dim3(SEQ / 128, DIM / 128, 4), 256, 0, stream>>>(P, Vt, denom, out);
}

// Round 10
// 172.168 us; speedup vs baseline: 1.4616x; 1.1169x over previous
//
#include <hip/hip_runtime.h>
#include <hip/hip_bf16.h>

using bf16 = __hip_bfloat16;
typedef __attribute__((ext_vector_type(4))) float f32x4;
typedef __attribute__((ext_vector_type(8))) short short8;

#define SEQ 4096
#define DIM 768

// Proven: fp32 in / fp32 out, bf16 internals. r10 = r7 (best measured: 167us;
// r8 direct-load and r9 atomic-accumulate both regressed) with one fix:
// score gets launch_bounds(256,4) so its 1024-block grid co-resides 4/CU
// (was capped at 3 by the bound; LDS 4x32KB=128<=160KB, regs 64+64<=128 fit).

// ---- fused fp32 -> bf16 canonicalization (RNE) + denom zeroing ----
__global__ void convert_all_kernel(const float* __restrict__ x,
                                   const float* __restrict__ wq,
                                   const float* __restrict__ wk,
                                   const float* __restrict__ wv,
                                   bf16* __restrict__ xc, bf16* __restrict__ wqc,
                                   bf16* __restrict__ wkc, bf16* __restrict__ wvc,
                                   float* __restrict__ denom) {
  const int XB = (SEQ * DIM) / 2048;   // 1536
  const int WB = (DIM * DIM) / 2048;   // 288
  int b = blockIdx.x;
  if (b == 0) {  // zero denom[4096]
    float4 z = {0.f, 0.f, 0.f, 0.f};
#pragma unroll
    for (int q = 0; q < 4; q++)
      *(float4*)(denom + threadIdx.x * 4 + q * 1024) = z;
  }
  const float* src; bf16* dst; int off;
  if (b < XB)               { src = x;  dst = xc;  off = b * 2048; }
  else if (b < XB + WB)     { src = wq; dst = wqc; off = (b - XB) * 2048; }
  else if (b < XB + 2 * WB) { src = wk; dst = wkc; off = (b - XB - WB) * 2048; }
  else                      { src = wv; dst = wvc; off = (b - XB - 2 * WB) * 2048; }
  int i = off + threadIdx.x * 8;
  float4 f0 = *(const float4*)(src + i);
  float4 f1 = *(const float4*)(src + i + 4);
  bf16 tmp[8];
  tmp[0] = __float2bfloat16(f0.x); tmp[1] = __float2bfloat16(f0.y);
  tmp[2] = __float2bfloat16(f0.z); tmp[3] = __float2bfloat16(f0.w);
  tmp[4] = __float2bfloat16(f1.x); tmp[5] = __float2bfloat16(f1.y);
  tmp[6] = __float2bfloat16(f1.z); tmp[7] = __float2bfloat16(f1.w);
  *(uint4*)(dst + i) = *(const uint4*)tmp;
}

// ============ BT-GEMM core (BK=64, two BK=32 planes, LDS-DMA) ============
__device__ __forceinline__ void gload_lds16(const bf16* g, bf16* l) {
  __builtin_amdgcn_global_load_lds(
      (const __attribute__((address_space(1))) void*)g,
      (__attribute__((address_space(3))) void*)l,
      16, 0, 0);
}

__device__ __forceinline__ void stage64(const bf16* g, int ldk, bf16* l,
                                        int wave, int lane) {
  int r = lane >> 2;            // 0..15
  int c = (lane & 3) * 8;       // 0,8,16,24
  const bf16* gw = g + (size_t)(wave * 32) * ldk;
  bf16* lw = l + wave * 1024;
#pragma unroll
  for (int h = 0; h < 2; h++)
#pragma unroll
    for (int s = 0; s < 2; s++)
      gload_lds16(gw + (size_t)(s * 16 + r) * ldk + h * 32 + c,
                  lw + h * 4096 + s * 512);
}

__device__ __forceinline__ void gemm_core(const bf16* __restrict__ A,
                                          const bf16* __restrict__ B,
                                          int ldk, int klen, int m0, int n0,
                                          f32x4 acc[4][4],
                                          bf16* lA, bf16* lB) {
  const int tid  = threadIdx.x;
  const int wave = tid >> 6, lane = tid & 63;
  const int wm = (wave & 1) * 64, wn = (wave >> 1) * 64;
  const int g = lane >> 4, lr = lane & 15;
  const bf16* Abase = A + (size_t)m0 * ldk;
  const bf16* Bbase = B + (size_t)n0 * ldk;
  for (int kk = 0; kk < klen; kk += 64) {
    stage64(Abase + kk, ldk, lA, wave, lane);
    stage64(Bbase + kk, ldk, lB, wave, lane);
    __syncthreads();  // vmcnt drain (DMA done) + barrier
#pragma unroll
    for (int h = 0; h < 2; h++) {
      short8 af[4], bfr[4];
#pragma unroll
      for (int i = 0; i < 4; i++)
        af[i] = *(const short8*)&lA[h * 4096 + (wm + i * 16 + lr) * 32 + g * 8];
#pragma unroll
      for (int j = 0; j < 4; j++)
        bfr[j] = *(const short8*)&lB[h * 4096 + (wn + j * 16 + lr) * 32 + g * 8];
#pragma unroll
      for (int i = 0; i < 4; i++)
#pragma unroll
        for (int j = 0; j < 4; j++)
          acc[i][j] = __builtin_amdgcn_mfma_f32_16x16x32_bf16(af[i], bfr[j], acc[i][j], 0, 0, 0);
    }
    __syncthreads();
  }
}

// C/D layout (verified m89/m91): col = lane&15, row = (lane>>4)*4 + reg.

// ---- K1: fused QKV projection. grid (32, 18). Q gets softmax scale folded;
// V written transposed via LDS transpose (coalesced Vt stores).
__global__ __launch_bounds__(256, 3) void qkv_kernel(
    const bf16* __restrict__ x, const bf16* __restrict__ Wq,
    const bf16* __restrict__ Wk, const bf16* __restrict__ Wv,
    bf16* __restrict__ Q, bf16* __restrict__ Kb, bf16* __restrict__ Vt) {
  __shared__ __align__(16) bf16 smem[16384];  // lA|lB for gemm; tile for transpose
  bf16* lA = smem;
  bf16* lB = smem + 8192;
  const int m0  = blockIdx.x * 128;
  const int n0g = blockIdx.y * 128;
  const int wsel = n0g / DIM;          // 0=Q 1=K 2=V (uniform per block)
  const int n0   = n0g % DIM;
  const bf16* W = (wsel == 0) ? Wq : (wsel == 1) ? Wk : Wv;
  f32x4 acc[4][4] = {};
  gemm_core(x, W, DIM, DIM, m0, n0, acc, lA, lB);

  const int tid = threadIdx.x, wave = tid >> 6, lane = tid & 63;
  const int wm = (wave & 1) * 64, wn = (wave >> 1) * 64;
  const int g = lane >> 4, lr = lane & 15;
  const float scale = 0.03608439182435161f;  // 1/sqrt(768)

  if (wsel == 2) {
    // Two-phase 128x64 LDS transpose; stride 67 spreads banks.
    bf16* tile = smem;
#pragma unroll
    for (int ph = 0; ph < 2; ph++) {
      __syncthreads();
      if ((wave >> 1) == ph) {
#pragma unroll
        for (int i = 0; i < 4; i++)
#pragma unroll
          for (int j = 0; j < 4; j++)
#pragma unroll
            for (int r = 0; r < 4; r++)
              tile[(wm + i * 16 + g * 4 + r) * 67 + j * 16 + lr] =
                  __float2bfloat16(acc[i][j][r]);
      }
      __syncthreads();
      int cl = tid >> 2;          // column within this 64-col half
      int r0 = (tid & 3) * 32;    // row segment
      bf16 vals[32];
#pragma unroll
      for (int k = 0; k < 32; k++) vals[k] = tile[(r0 + k) * 67 + cl];
      bf16* dst = Vt + (size_t)(n0 + ph * 64 + cl) * SEQ + m0 + r0;
#pragma unroll
      for (int q = 0; q < 4; q++)
        *(uint4*)(dst + q * 8) = *(const uint4*)(vals + q * 8);
    }
  } else {
    bf16* dstm = (wsel == 0) ? Q : Kb;
    float fs = (wsel == 0) ? scale : 1.0f;
#pragma unroll
    for (int i = 0; i < 4; i++)
#pragma unroll
      for (int j = 0; j < 4; j++)
#pragma unroll
        for (int r = 0; r < 4; r++) {
          int row = m0 + wm + i * 16 + g * 4 + r;
          int col = n0 + wn + j * 16 + lr;
          dstm[row * DIM + col] = __float2bfloat16(acc[i][j][r] * fs);
        }
  }
}

// ---- K2: S = Q K^T; P = exp(S) (|logit| <~ 2, no max-sub); row sums -> denom.
// grid (32,32) = 4 blocks/CU: bounds (256,4) so all 4 co-reside.
__global__ __launch_bounds__(256, 4) void score_kernel(
    const bf16* __restrict__ Q, const bf16* __restrict__ Kb,
    bf16* __restrict__ P, float* __restrict__ denom) {
  __shared__ __align__(16) bf16 smem[16384];
  bf16* lA = smem;
  bf16* lB = smem + 8192;
  const int m0 = blockIdx.x * 128;
  const int n0 = blockIdx.y * 128;
  f32x4 acc[4][4] = {};
  gemm_core(Q, Kb, DIM, DIM, m0, n0, acc, lA, lB);

  const int tid = threadIdx.x, wave = tid >> 6, lane = tid & 63;
  const int wm = (wave & 1) * 64, wn = (wave >> 1) * 64;
  const int g = lane >> 4, lr = lane & 15;
#pragma unroll
  for (int i = 0; i < 4; i++) {
    float rsum[4] = {0.f, 0.f, 0.f, 0.f};
#pragma unroll
    for (int j = 0; j < 4; j++)
#pragma unroll
      for (int r = 0; r < 4; r++) {
        float p = __expf(acc[i][j][r]);
        int row = m0 + wm + i * 16 + g * 4 + r;
        int col = n0 + wn + j * 16 + lr;
        P[(size_t)row * SEQ + col] = __float2bfloat16(p);
        rsum[r] += p;
      }
#pragma unroll
    for (int r = 0; r < 4; r++) {
      float s = rsum[r];
      s += __shfl_xor(s, 1);
      s += __shfl_xor(s, 2);
      s += __shfl_xor(s, 4);
      s += __shfl_xor(s, 8);
      if (lr == 0) atomicAdd(&denom[m0 + wm + i * 16 + g * 4 + r], s);
    }
  }
}

// ---- K3a: split-K PV. grid (32, 6, 4); z picks K-chunk of 1024. bf16 partials.
__global__ __launch_bounds__(256, 3) void pv_kernel(
    const bf16* __restrict__ P, const bf16* __restrict__ Vt,
    bf16* __restrict__ partial) {
  __shared__ __align__(16) bf16 smem[16384];
  bf16* lA = smem;
  bf16* lB = smem + 8192;
  const int m0 = blockIdx.x * 128;
  const int n0 = blockIdx.y * 128;
  const int kbase = blockIdx.z * (SEQ / 4);
  f32x4 acc[4][4] = {};
  gemm_core(P + kbase, Vt + kbase, SEQ, SEQ / 4, m0, n0, acc, lA, lB);

  bf16* pout = partial + (size_t)blockIdx.z * SEQ * DIM;
  const int tid = threadIdx.x, wave = tid >> 6, lane = tid & 63;
  const int wm = (wave & 1) * 64, wn = (wave >> 1) * 64;
  const int g = lane >> 4, lr = lane & 15;
#pragma unroll
  for (int i = 0; i < 4; i++)
#pragma unroll
    for (int j = 0; j < 4; j++)
#pragma unroll
      for (int r = 0; r < 4; r++) {
        int row = m0 + wm + i * 16 + g * 4 + r;
        int col = n0 + wn + j * 16 + lr;
        pout[row * DIM + col] = __float2bfloat16(acc[i][j][r]);
      }
}

// ---- K3b: out = (sum_z partial[z]) / denom[row]. 8 elems/thread.
__global__ __launch_bounds__(256) void reduce_kernel(
    const bf16* __restrict__ partial, const float* __restrict__ denom,
    float* __restrict__ out) {
  const size_t stride = (size_t)SEQ * DIM;
  int i = (blockIdx.x * 256 + threadIdx.x) * 8;
  uint4 u0 = *(const uint4*)(partial + i);
  uint4 u1 = *(const uint4*)(partial + stride + i);
  uint4 u2 = *(const uint4*)(partial + 2 * stride + i);
  uint4 u3 = *(const uint4*)(partial + 3 * stride + i);
  bf16 a0[8], a1[8], a2[8], a3[8];
  *(uint4*)a0 = u0; *(uint4*)a1 = u1; *(uint4*)a2 = u2; *(uint4*)a3 = u3;
  float inv = 1.0f / denom[i / DIM];   // 8 | DIM: all 8 elems same row
  float o[8];
#pragma unroll
  for (int k = 0; k < 8; k++)
    o[k] = (__bfloat162float(a0[k]) + __bfloat162float(a1[k]) +
            __bfloat162float(a2[k]) + __bfloat162float(a3[k])) * inv;
  *(float4*)(out + i)     = *(const float4*)(o);
  *(float4*)(out + i + 4) = *(const float4*)(o + 4);
}

extern "C" void kernel_launch(void* const* d_in, const int* in_sizes, int n_in,
                              void* d_out, int out_size, void* d_ws, size_t ws_size,
                              hipStream_t stream) {
  const float* x_raw  = (const float*)d_in[0];
  const float* Wq_raw = (const float*)d_in[1];
  const float* Wk_raw = (const float*)d_in[2];
  const float* Wv_raw = (const float*)d_in[3];
  float* out = (float*)d_out;

  // ws layout (~86 MB):
  //   xc bf16 [4096][768], Wqc/Wkc/Wvc bf16 [768][768]
  //   Q bf16 [4096][768] (pre-scaled), Kb bf16 [4096][768], Vt bf16 [768][4096]
  //   P bf16 [4096][4096], denom f32 [4096], partial bf16 [4][4096][768]
  bf16* xc  = (bf16*)d_ws;
  bf16* Wqc = xc  + (size_t)SEQ * DIM;
  bf16* Wkc = Wqc + (size_t)DIM * DIM;
  bf16* Wvc = Wkc + (size_t)DIM * DIM;
  bf16* Q   = Wvc + (size_t)DIM * DIM;
  bf16* Kb  = Q   + (size_t)SEQ * DIM;
  bf16* Vt  = Kb  + (size_t)SEQ * DIM;
  bf16* P   = Vt  + (size_t)DIM * SEQ;
  float* denom  = (float*)(P + (size_t)SEQ * SEQ);
  bf16* partial = (bf16*)(denom + SEQ);

  const int nx = SEQ * DIM;   // 3,145,728
  const int nw = DIM * DIM;   //   589,824
  const int conv_blocks = nx / 2048 + 3 * (nw / 2048);  // 2400

  convert_all_kernel<<<conv_blocks, 256, 0, stream>>>(
      x_raw, Wq_raw, Wk_raw, Wv_raw, xc, Wqc, Wkc, Wvc, denom);
  qkv_kernel<<<dim3(SEQ / 128, 2304 / 128), 256, 0, stream>>>(xc, Wqc, Wkc, Wvc, Q, Kb, Vt);
  score_kernel<<<dim3(SEQ / 128, SEQ / 128), 256, 0, stream>>>(Q, Kb, P, denom);
  pv_kernel<<<dim3(SEQ / 128, DIM / 128, 4), 256, 0, stream>>>(P, Vt, partial);
  reduce_kernel<<<nx / 8 / 256, 256, 0, stream>>>(partial, denom, out);
}

// Round 11
// 166.083 us; speedup vs baseline: 1.5151x; 1.0366x over previous
//
#include <hip/hip_runtime.h>
#include <hip/hip_bf16.h>

using bf16 = __hip_bfloat16;
typedef __attribute__((ext_vector_type(4))) float f32x4;
typedef __attribute__((ext_vector_type(8))) short short8;

#define SEQ 4096
#define DIM 768

// Proven: fp32 in / fp32 out, bf16 internals. r11 = r7 (best: 167us) +
// XCD-aware block swizzle (id%8 -> XCD heuristic): each XCD owns a 4-wide
// slab of M-tiles so A-tiles stay hot in its 4MB L2 and B-tiles are reused
// across consecutive same-XCD blocks. Attacks L2<-L3 re-fetch (invisible in
// FETCH_SIZE), which models the 650-vs-912 TF gap vs m97 at 4096^3.
// r9 atomics / r8 direct-load / r10 bounds(4) all measured regressions.

// ---- fused fp32 -> bf16 canonicalization (RNE) + denom zeroing ----
__global__ void convert_all_kernel(const float* __restrict__ x,
                                   const float* __restrict__ wq,
                                   const float* __restrict__ wk,
                                   const float* __restrict__ wv,
                                   bf16* __restrict__ xc, bf16* __restrict__ wqc,
                                   bf16* __restrict__ wkc, bf16* __restrict__ wvc,
                                   float* __restrict__ denom) {
  const int XB = (SEQ * DIM) / 2048;   // 1536
  const int WB = (DIM * DIM) / 2048;   // 288
  int b = blockIdx.x;
  if (b == 0) {  // zero denom[4096]
    float4 z = {0.f, 0.f, 0.f, 0.f};
#pragma unroll
    for (int q = 0; q < 4; q++)
      *(float4*)(denom + threadIdx.x * 4 + q * 1024) = z;
  }
  const float* src; bf16* dst; int off;
  if (b < XB)               { src = x;  dst = xc;  off = b * 2048; }
  else if (b < XB + WB)     { src = wq; dst = wqc; off = (b - XB) * 2048; }
  else if (b < XB + 2 * WB) { src = wk; dst = wkc; off = (b - XB - WB) * 2048; }
  else                      { src = wv; dst = wvc; off = (b - XB - 2 * WB) * 2048; }
  int i = off + threadIdx.x * 8;
  float4 f0 = *(const float4*)(src + i);
  float4 f1 = *(const float4*)(src + i + 4);
  bf16 tmp[8];
  tmp[0] = __float2bfloat16(f0.x); tmp[1] = __float2bfloat16(f0.y);
  tmp[2] = __float2bfloat16(f0.z); tmp[3] = __float2bfloat16(f0.w);
  tmp[4] = __float2bfloat16(f1.x); tmp[5] = __float2bfloat16(f1.y);
  tmp[6] = __float2bfloat16(f1.z); tmp[7] = __float2bfloat16(f1.w);
  *(uint4*)(dst + i) = *(const uint4*)tmp;
}

// ============ BT-GEMM core (BK=64, two BK=32 planes, LDS-DMA) ============
__device__ __forceinline__ void gload_lds16(const bf16* g, bf16* l) {
  __builtin_amdgcn_global_load_lds(
      (const __attribute__((address_space(1))) void*)g,
      (__attribute__((address_space(3))) void*)l,
      16, 0, 0);
}

__device__ __forceinline__ void stage64(const bf16* g, int ldk, bf16* l,
                                        int wave, int lane) {
  int r = lane >> 2;            // 0..15
  int c = (lane & 3) * 8;       // 0,8,16,24
  const bf16* gw = g + (size_t)(wave * 32) * ldk;
  bf16* lw = l + wave * 1024;
#pragma unroll
  for (int h = 0; h < 2; h++)
#pragma unroll
    for (int s = 0; s < 2; s++)
      gload_lds16(gw + (size_t)(s * 16 + r) * ldk + h * 32 + c,
                  lw + h * 4096 + s * 512);
}

__device__ __forceinline__ void gemm_core(const bf16* __restrict__ A,
                                          const bf16* __restrict__ B,
                                          int ldk, int klen, int m0, int n0,
                                          f32x4 acc[4][4],
                                          bf16* lA, bf16* lB) {
  const int tid  = threadIdx.x;
  const int wave = tid >> 6, lane = tid & 63;
  const int wm = (wave & 1) * 64, wn = (wave >> 1) * 64;
  const int g = lane >> 4, lr = lane & 15;
  const bf16* Abase = A + (size_t)m0 * ldk;
  const bf16* Bbase = B + (size_t)n0 * ldk;
  for (int kk = 0; kk < klen; kk += 64) {
    stage64(Abase + kk, ldk, lA, wave, lane);
    stage64(Bbase + kk, ldk, lB, wave, lane);
    __syncthreads();  // vmcnt drain (DMA done) + barrier
#pragma unroll
    for (int h = 0; h < 2; h++) {
      short8 af[4], bfr[4];
#pragma unroll
      for (int i = 0; i < 4; i++)
        af[i] = *(const short8*)&lA[h * 4096 + (wm + i * 16 + lr) * 32 + g * 8];
#pragma unroll
      for (int j = 0; j < 4; j++)
        bfr[j] = *(const short8*)&lB[h * 4096 + (wn + j * 16 + lr) * 32 + g * 8];
#pragma unroll
      for (int i = 0; i < 4; i++)
#pragma unroll
        for (int j = 0; j < 4; j++)
          acc[i][j] = __builtin_amdgcn_mfma_f32_16x16x32_bf16(af[i], bfr[j], acc[i][j], 0, 0, 0);
    }
    __syncthreads();
  }
}

// C/D layout (verified m89/m91): col = lane&15, row = (lane>>4)*4 + reg.

// ---- K1: fused QKV projection. grid (32, 18), XCD-swizzled. Q gets softmax
// scale folded; V written transposed via LDS transpose.
__global__ __launch_bounds__(256, 3) void qkv_kernel(
    const bf16* __restrict__ x, const bf16* __restrict__ Wq,
    const bf16* __restrict__ Wk, const bf16* __restrict__ Wv,
    bf16* __restrict__ Q, bf16* __restrict__ Kb, bf16* __restrict__ Vt) {
  __shared__ __align__(16) bf16 smem[16384];  // lA|lB for gemm; tile for transpose
  bf16* lA = smem;
  bf16* lB = smem + 8192;
  // swizzle: XCD (id%8) gets m-slab of 4 tiles x all 18 n-tiles (x-slab hot in L2)
  const int id  = blockIdx.y * 32 + blockIdx.x;  // 0..575
  const int xcd = id & 7;
  const int k   = id >> 3;                       // 0..71
  const int m0  = (xcd * 4 + (k & 3)) * 128;
  const int n0g = (k >> 2) * 128;                // 0..17 tiles
  const int wsel = n0g / DIM;          // 0=Q 1=K 2=V (uniform per block)
  const int n0   = n0g % DIM;
  const bf16* W = (wsel == 0) ? Wq : (wsel == 1) ? Wk : Wv;
  f32x4 acc[4][4] = {};
  gemm_core(x, W, DIM, DIM, m0, n0, acc, lA, lB);

  const int tid = threadIdx.x, wave = tid >> 6, lane = tid & 63;
  const int wm = (wave & 1) * 64, wn = (wave >> 1) * 64;
  const int g = lane >> 4, lr = lane & 15;
  const float scale = 0.03608439182435161f;  // 1/sqrt(768)

  if (wsel == 2) {
    // Two-phase 128x64 LDS transpose; stride 67 spreads banks.
    bf16* tile = smem;
#pragma unroll
    for (int ph = 0; ph < 2; ph++) {
      __syncthreads();
      if ((wave >> 1) == ph) {
#pragma unroll
        for (int i = 0; i < 4; i++)
#pragma unroll
          for (int j = 0; j < 4; j++)
#pragma unroll
            for (int r = 0; r < 4; r++)
              tile[(wm + i * 16 + g * 4 + r) * 67 + j * 16 + lr] =
                  __float2bfloat16(acc[i][j][r]);
      }
      __syncthreads();
      int cl = tid >> 2;          // column within this 64-col half
      int r0 = (tid & 3) * 32;    // row segment
      bf16 vals[32];
#pragma unroll
      for (int q = 0; q < 32; q++) vals[q] = tile[(r0 + q) * 67 + cl];
      bf16* dst = Vt + (size_t)(n0 + ph * 64 + cl) * SEQ + m0 + r0;
#pragma unroll
      for (int q = 0; q < 4; q++)
        *(uint4*)(dst + q * 8) = *(const uint4*)(vals + q * 8);
    }
  } else {
    bf16* dstm = (wsel == 0) ? Q : Kb;
    float fs = (wsel == 0) ? scale : 1.0f;
#pragma unroll
    for (int i = 0; i < 4; i++)
#pragma unroll
      for (int j = 0; j < 4; j++)
#pragma unroll
        for (int r = 0; r < 4; r++) {
          int row = m0 + wm + i * 16 + g * 4 + r;
          int col = n0 + wn + j * 16 + lr;
          dstm[row * DIM + col] = __float2bfloat16(acc[i][j][r] * fs);
        }
  }
}

// ---- K2: S = Q K^T; P = exp(S); row sums -> denom. grid (32,32), XCD-swizzled.
__global__ __launch_bounds__(256, 3) void score_kernel(
    const bf16* __restrict__ Q, const bf16* __restrict__ Kb,
    bf16* __restrict__ P, float* __restrict__ denom) {
  __shared__ __align__(16) bf16 smem[16384];
  bf16* lA = smem;
  bf16* lB = smem + 8192;
  // swizzle: XCD (id%8) gets m-slab of 4 Q-tiles (786KB, L2-hot) x all 32 n.
  const int id  = blockIdx.y * 32 + blockIdx.x;  // 0..1023
  const int xcd = id & 7;
  const int k   = id >> 3;                       // 0..127
  const int m0  = (xcd * 4 + (k & 3)) * 128;
  const int n0  = (k >> 2) * 128;
  f32x4 acc[4][4] = {};
  gemm_core(Q, Kb, DIM, DIM, m0, n0, acc, lA, lB);

  const int tid = threadIdx.x, wave = tid >> 6, lane = tid & 63;
  const int wm = (wave & 1) * 64, wn = (wave >> 1) * 64;
  const int g = lane >> 4, lr = lane & 15;
#pragma unroll
  for (int i = 0; i < 4; i++) {
    float rsum[4] = {0.f, 0.f, 0.f, 0.f};
#pragma unroll
    for (int j = 0; j < 4; j++)
#pragma unroll
      for (int r = 0; r < 4; r++) {
        float p = __expf(acc[i][j][r]);
        int row = m0 + wm + i * 16 + g * 4 + r;
        int col = n0 + wn + j * 16 + lr;
        P[(size_t)row * SEQ + col] = __float2bfloat16(p);
        rsum[r] += p;
      }
#pragma unroll
    for (int r = 0; r < 4; r++) {
      float s = rsum[r];
      s += __shfl_xor(s, 1);
      s += __shfl_xor(s, 2);
      s += __shfl_xor(s, 4);
      s += __shfl_xor(s, 8);
      if (lr == 0) atomicAdd(&denom[m0 + wm + i * 16 + g * 4 + r], s);
    }
  }
}

// ---- K3a: split-K PV. grid (32, 6, 4), XCD-swizzled. bf16 partials.
__global__ __launch_bounds__(256, 3) void pv_kernel(
    const bf16* __restrict__ P, const bf16* __restrict__ Vt,
    bf16* __restrict__ partial) {
  __shared__ __align__(16) bf16 smem[16384];
  bf16* lA = smem;
  bf16* lB = smem + 8192;
  // swizzle: XCD gets 3 (z,n) pairs x all 32 m: Vt chunk (256KB) L2-hot
  // across the 32 consecutive same-XCD blocks that reuse it.
  const int id  = (blockIdx.z * 6 + blockIdx.y) * 32 + blockIdx.x;  // 0..767
  const int xcd = id & 7;
  const int k   = id >> 3;          // 0..95
  const int m0  = (k & 31) * 128;
  const int pairid = xcd * 3 + (k >> 5);  // 0..23
  const int zz  = pairid / 6;
  const int n0  = (pairid % 6) * 128;
  const int kbase = zz * (SEQ / 4);
  f32x4 acc[4][4] = {};
  gemm_core(P + kbase, Vt + kbase, SEQ, SEQ / 4, m0, n0, acc, lA, lB);

  bf16* pout = partial + (size_t)zz * SEQ * DIM;
  const int tid = threadIdx.x, wave = tid >> 6, lane = tid & 63;
  const int wm = (wave & 1) * 64, wn = (wave >> 1) * 64;
  const int g = lane >> 4, lr = lane & 15;
#pragma unroll
  for (int i = 0; i < 4; i++)
#pragma unroll
    for (int j = 0; j < 4; j++)
#pragma unroll
      for (int r = 0; r < 4; r++) {
        int row = m0 + wm + i * 16 + g * 4 + r;
        int col = n0 + wn + j * 16 + lr;
        pout[row * DIM + col] = __float2bfloat16(acc[i][j][r]);
      }
}

// ---- K3b: out = (sum_z partial[z]) / denom[row]. 8 elems/thread.
__global__ __launch_bounds__(256) void reduce_kernel(
    const bf16* __restrict__ partial, const float* __restrict__ denom,
    float* __restrict__ out) {
  const size_t stride = (size_t)SEQ * DIM;
  int i = (blockIdx.x * 256 + threadIdx.x) * 8;
  uint4 u0 = *(const uint4*)(partial + i);
  uint4 u1 = *(const uint4*)(partial + stride + i);
  uint4 u2 = *(const uint4*)(partial + 2 * stride + i);
  uint4 u3 = *(const uint4*)(partial + 3 * stride + i);
  bf16 a0[8], a1[8], a2[8], a3[8];
  *(uint4*)a0 = u0; *(uint4*)a1 = u1; *(uint4*)a2 = u2; *(uint4*)a3 = u3;
  float inv = 1.0f / denom[i / DIM];   // 8 | DIM: all 8 elems same row
  float o[8];
#pragma unroll
  for (int k = 0; k < 8; k++)
    o[k] = (__bfloat162float(a0[k]) + __bfloat162float(a1[k]) +
            __bfloat162float(a2[k]) + __bfloat162float(a3[k])) * inv;
  *(float4*)(out + i)     = *(const float4*)(o);
  *(float4*)(out + i + 4) = *(const float4*)(o + 4);
}

extern "C" void kernel_launch(void* const* d_in, const int* in_sizes, int n_in,
                              void* d_out, int out_size, void* d_ws, size_t ws_size,
                              hipStream_t stream) {
  const float* x_raw  = (const float*)d_in[0];
  const float* Wq_raw = (const float*)d_in[1];
  const float* Wk_raw = (const float*)d_in[2];
  const float* Wv_raw = (const float*)d_in[3];
  float* out = (float*)d_out;

  // ws layout (~86 MB):
  //   xc bf16 [4096][768], Wqc/Wkc/Wvc bf16 [768][768]
  //   Q bf16 [4096][768] (pre-scaled), Kb bf16 [4096][768], Vt bf16 [768][4096]
  //   P bf16 [4096][4096], denom f32 [4096], partial bf16 [4][4096][768]
  bf16* xc  = (bf16*)d_ws;
  bf16* Wqc = xc  + (size_t)SEQ * DIM;
  bf16* Wkc = Wqc + (size_t)DIM * DIM;
  bf16* Wvc = Wkc + (size_t)DIM * DIM;
  bf16* Q   = Wvc + (size_t)DIM * DIM;
  bf16* Kb  = Q   + (size_t)SEQ * DIM;
  bf16* Vt  = Kb  + (size_t)SEQ * DIM;
  bf16* P   = Vt  + (size_t)DIM * SEQ;
  float* denom  = (float*)(P + (size_t)SEQ * SEQ);
  bf16* partial = (bf16*)(denom + SEQ);

  const int nx = SEQ * DIM;   // 3,145,728
  const int nw = DIM * DIM;   //   589,824
  const int conv_blocks = nx / 2048 + 3 * (nw / 2048);  // 2400

  convert_all_kernel<<<conv_blocks, 256, 0, stream>>>(
      x_raw, Wq_raw, Wk_raw, Wv_raw, xc, Wqc, Wkc, Wvc, denom);
  qkv_kernel<<<dim3(SEQ / 128, 2304 / 128), 256, 0, stream>>>(xc, Wqc, Wkc, Wvc, Q, Kb, Vt);
  score_kernel<<<dim3(SEQ / 128, SEQ / 128), 256, 0, stream>>>(Q, Kb, P, denom);
  pv_kernel<<<dim3(SEQ / 128, DIM / 128, 4), 256, 0, stream>>>(P, Vt, partial);
  reduce_kernel<<<nx / 8 / 256, 256, 0, stream>>>(partial, denom, out);
}